// Round 6
// baseline (1142.380 us; speedup 1.0000x reference)
//
#include <hip/hip_runtime.h>
#include <math.h>

#define N_NODES 50000
#define N_EDGES 800000
#define TPB 256

// ---------------- register-blocked f32 GEMM ----------------
// out[M,NO] = act( [A1 | A2] @ [W1 ; W2] + bias ),  K = K1 + K2
// 128x128 block tile, 256 threads, 8x8 micro-tile, BK=16.
// LDS: sA[BK][BM+4] (A transposed), sB[BK][BN+4]. Reads are ds_read_b128,
// 2-way bank aliasing max (free). Inner loop: 64 FMA per 4 b128 per thread.
template<int ACT>
__global__ __launch_bounds__(256) void gemm_f32(
    const float* __restrict__ A1, int K1, const float* __restrict__ A2, int K2,
    const float* __restrict__ W1, const float* __restrict__ W2,
    const float* __restrict__ bias, float* __restrict__ out, int NO) {
    constexpr int BM = 128, BN = 128, BK = 16;
    __shared__ float sA[BK][BM + 4];
    __shared__ float sB[BK][BN + 4];
    const int K = K1 + K2;
    const int tid = threadIdx.x;
    const int tm = tid & 15, tn = tid >> 4;      // 16x16 thread grid
    const int row0 = blockIdx.y * BM;
    const int col0 = blockIdx.x * BN;
    float acc[8][8] = {};

    for (int k0 = 0; k0 < K; k0 += BK) {
        // stage A (BM x BK, transposed into sA[kk][m]); coalesced along k
#pragma unroll
        for (int j = 0; j < 8; ++j) {
            int e = tid + j * 256;
            int kk = e & 15, m = e >> 4;
            int kg = k0 + kk, mg = row0 + m;
            float v = 0.f;
            if (mg < N_NODES) {
                if (kg < K1) v = A1[(size_t)mg * K1 + kg];
                else if (kg < K) v = A2[(size_t)mg * K2 + (kg - K1)];
            }
            sA[kk][m] = v;
        }
        // stage B (BK x BN); coalesced along n
#pragma unroll
        for (int j = 0; j < 8; ++j) {
            int e = tid + j * 256;
            int n = e & 127, kk = e >> 7;
            int kg = k0 + kk, ng = col0 + n;
            float v = 0.f;
            if (kg < K1) v = W1[(size_t)kg * NO + ng];
            else if (kg < K) v = W2[(size_t)(kg - K1) * NO + ng];
            sB[kk][n] = v;
        }
        __syncthreads();
#pragma unroll
        for (int kk = 0; kk < BK; ++kk) {
            float a[8], b[8];
#pragma unroll
            for (int i = 0; i < 8; ++i) a[i] = sA[kk][tm * 8 + i];
#pragma unroll
            for (int j2 = 0; j2 < 8; ++j2) b[j2] = sB[kk][tn * 8 + j2];
#pragma unroll
            for (int i = 0; i < 8; ++i)
#pragma unroll
                for (int j2 = 0; j2 < 8; ++j2)
                    acc[i][j2] = fmaf(a[i], b[j2], acc[i][j2]);
        }
        __syncthreads();
    }
#pragma unroll
    for (int i = 0; i < 8; ++i) {
        int mg = row0 + tm * 8 + i;
        if (mg >= N_NODES) continue;
#pragma unroll
        for (int j2 = 0; j2 < 8; ++j2) {
            int ng = col0 + tn * 8 + j2;
            float v = acc[i][j2] + (bias ? bias[ng] : 0.f);
            if (ACT) v = fmaxf(v, 0.f);
            out[(size_t)mg * NO + ng] = v;
        }
    }
}

// ---------------- CSR construction ----------------
__global__ void hist_k(const int* __restrict__ dst, int* __restrict__ deg) {
    int e = blockIdx.x * TPB + threadIdx.x;
    if (e < N_EDGES) atomicAdd(&deg[dst[e]], 1);
}

// single-block exclusive scan over deg -> rowptr (N_NODES+1 entries)
__global__ void scan_k(const int* __restrict__ deg, int* __restrict__ rowptr) {
    __shared__ int part[1024];
    const int tid = threadIdx.x;                     // 1024 threads
    const int CH = (N_NODES + 1023) / 1024;          // 49
    const int base = tid * CH;
    int s = 0;
    for (int i = 0; i < CH; ++i) {
        int idx = base + i;
        if (idx < N_NODES) s += deg[idx];
    }
    part[tid] = s;
    __syncthreads();
    for (int off = 1; off < 1024; off <<= 1) {
        int v = (tid >= off) ? part[tid - off] : 0;
        __syncthreads();
        part[tid] += v;
        __syncthreads();
    }
    int run = (tid == 0) ? 0 : part[tid - 1];
    for (int i = 0; i < CH; ++i) {
        int idx = base + i;
        if (idx < N_NODES) {
            rowptr[idx] = run;
            run += deg[idx];
        }
    }
    if (tid == 1023) rowptr[N_NODES] = run;
}

__global__ void fill_k(const int* __restrict__ src, const int* __restrict__ dst,
                       const int* __restrict__ rowptr, int* __restrict__ fill,
                       int* __restrict__ csr_src) {
    int e = blockIdx.x * TPB + threadIdx.x;
    if (e >= N_EDGES) return;
    int d = dst[e];
    int pos = rowptr[d] + atomicAdd(&fill[d], 1);
    csr_src[pos] = src[e];
}

// ---------------- gather aggregations (no scatter atomics) ----------------
template<int F, int BLK>
__global__ void gather_mean(const int* __restrict__ rowptr, const int* __restrict__ csr_src,
                            const float* __restrict__ feat, float* __restrict__ out) {
    int n = blockIdx.x;
    int c = threadIdx.x;
    if (c >= F) return;
    int e0 = rowptr[n], e1 = rowptr[n + 1];
    float acc = 0.f;
    for (int e = e0; e < e1; ++e)
        acc += feat[(size_t)csr_src[e] * F + c];
    out[(size_t)n * F + c] = acc / fmaxf((float)(e1 - e0), 1.0f);
}

// per-(node,head) attention scores
__global__ void att_scores(const float* __restrict__ h, const float* __restrict__ att_src,
                           const float* __restrict__ att_dst, float* __restrict__ as_,
                           float* __restrict__ ad_) {
    int idx = blockIdx.x * TPB + threadIdx.x;
    if (idx >= N_NODES * 4) return;
    int n = idx >> 2, hd = idx & 3;
    const float* row = h + (size_t)n * 128 + hd * 32;
    float sa = 0.f, sd = 0.f;
    for (int c = 0; c < 32; ++c) {
        float v = row[c];
        sa = fmaf(v, att_src[hd * 32 + c], sa);
        sd = fmaf(v, att_dst[hd * 32 + c], sd);
    }
    as_[idx] = sa;
    ad_[idx] = sd;
}

// fused GAT aggregation: online softmax per thread + weighted gather + ELU
__global__ void gat_gather(const int* __restrict__ rowptr, const int* __restrict__ csr_src,
                           const float* __restrict__ h, const float* __restrict__ as_,
                           const float* __restrict__ ad_, const float* __restrict__ gb,
                           float* __restrict__ out) {
    int n = blockIdx.x;
    int c = threadIdx.x;           // 0..127
    int hd = c >> 5;
    int e0 = rowptr[n], e1 = rowptr[n + 1];
    float ad = ad_[n * 4 + hd];
    float m = -INFINITY, s = 0.f, acc = 0.f;
    for (int e = e0; e < e1; ++e) {
        int sn = csr_src[e];
        float a = as_[sn * 4 + hd] + ad;
        a = a >= 0.f ? a : 0.2f * a;              // leaky_relu 0.2
        if (a > m) {                               // online softmax rescale
            float sc = __expf(m - a);
            s *= sc; acc *= sc; m = a;
        }
        float ex = __expf(a - m);
        s += ex;
        acc = fmaf(h[(size_t)sn * 128 + c], ex, acc);
    }
    float v = acc / (s + 1e-16f) + gb[c];
    out[(size_t)n * 128 + c] = v > 0.f ? v : expm1f(v);
}

// classifier: [N,256] @ [256,5] + b
__global__ void cls_k(const float* __restrict__ h, const float* __restrict__ W,
                      const float* __restrict__ b, float* __restrict__ out) {
    __shared__ float sW[256 * 5];
    for (int i = threadIdx.x; i < 1280; i += TPB) sW[i] = W[i];
    __syncthreads();
    int n = blockIdx.x * TPB + threadIdx.x;
    if (n >= N_NODES) return;
    const float4* row = (const float4*)(h + (size_t)n * 256);
    float acc[5] = {0.f, 0.f, 0.f, 0.f, 0.f};
    for (int k4 = 0; k4 < 64; ++k4) {
        float4 v = row[k4];
        const float* w = &sW[k4 * 4 * 5];
#pragma unroll
        for (int c = 0; c < 5; ++c) acc[c] = fmaf(v.x, w[c], acc[c]);
#pragma unroll
        for (int c = 0; c < 5; ++c) acc[c] = fmaf(v.y, w[5 + c], acc[c]);
#pragma unroll
        for (int c = 0; c < 5; ++c) acc[c] = fmaf(v.z, w[10 + c], acc[c]);
#pragma unroll
        for (int c = 0; c < 5; ++c) acc[c] = fmaf(v.w, w[15 + c], acc[c]);
    }
#pragma unroll
    for (int c = 0; c < 5; ++c) out[(size_t)n * 5 + c] = acc[c] + b[c];
}

extern "C" void kernel_launch(void* const* d_in, const int* in_sizes, int n_in,
                              void* d_out, int out_size, void* d_ws, size_t ws_size,
                              hipStream_t stream) {
    const float* x    = (const float*)d_in[0];
    const int*   ei   = (const int*)d_in[1];
    const float* s1Wl = (const float*)d_in[2];
    const float* s1Wr = (const float*)d_in[3];
    const float* s1b  = (const float*)d_in[4];
    const float* gW   = (const float*)d_in[5];
    const float* gas  = (const float*)d_in[6];
    const float* gad  = (const float*)d_in[7];
    const float* gb   = (const float*)d_in[8];
    const float* s2Wl = (const float*)d_in[9];
    const float* s2Wr = (const float*)d_in[10];
    const float* s2b  = (const float*)d_in[11];
    const float* clsW = (const float*)d_in[12];
    const float* clsb = (const float*)d_in[13];
    float* out = (float*)d_out;
    const int* src = ei;            // edge_index[0]
    const int* dst = ei + N_EDGES;  // edge_index[1]

    // ---- workspace layout (all fully rewritten each call; no stale reads) ----
    float* ws  = (float*)d_ws;
    float* A   = ws;                                  // N*256 (h1, then h3)
    float* C   = A + (size_t)N_NODES * 256;           // N*128 (gat h; later sage2 mean)
    float* D   = C + (size_t)N_NODES * 128;           // N*128 (sage1 mean(20); later gat out/h2)
    float* as_ = D + (size_t)N_NODES * 128;           // N*4
    float* ad_ = as_ + N_NODES * 4;                   // N*4
    int* deg     = (int*)(ad_ + N_NODES * 4);         // N
    int* fill    = deg + N_NODES;                     // N
    int* rowptr  = fill + N_NODES;                    // N+1
    int* csr_src = rowptr + N_NODES + 1;              // E

    const int MB = (N_NODES + 127) / 128;             // 391 row-blocks

    // ---- CSR build ----
    hipMemsetAsync(deg, 0, N_NODES * sizeof(int), stream);
    hipMemsetAsync(fill, 0, N_NODES * sizeof(int), stream);
    hist_k<<<(N_EDGES + TPB - 1) / TPB, TPB, 0, stream>>>(dst, deg);
    scan_k<<<1, 1024, 0, stream>>>(deg, rowptr);
    fill_k<<<(N_EDGES + TPB - 1) / TPB, TPB, 0, stream>>>(src, dst, rowptr, fill, csr_src);

    // ---- SAGE1:  A = relu([mean(x) | x] @ [Wl ; Wr] + b),  K = 20+20 ----
    gather_mean<20, 64><<<N_NODES, 64, 0, stream>>>(rowptr, csr_src, x, D);
    gemm_f32<1><<<dim3(2, MB), 256, 0, stream>>>(D, 20, x, 20, s1Wl, s1Wr, s1b, A, 256);

    // ---- GAT:  C = A @ gW,  K = 256 ----
    gemm_f32<0><<<dim3(1, MB), 256, 0, stream>>>(A, 256, nullptr, 0, gW, nullptr,
                                                 nullptr, C, 128);
    att_scores<<<(N_NODES * 4 + TPB - 1) / TPB, TPB, 0, stream>>>(C, gas, gad, as_, ad_);
    gat_gather<<<N_NODES, 128, 0, stream>>>(rowptr, csr_src, C, as_, ad_, gb, D);

    // ---- SAGE2:  A = relu([mean(D) | D] @ [Wl ; Wr] + b),  K = 128+128 ----
    gather_mean<128, 128><<<N_NODES, 128, 0, stream>>>(rowptr, csr_src, D, C);
    gemm_f32<1><<<dim3(2, MB), 256, 0, stream>>>(C, 128, D, 128, s2Wl, s2Wr, s2b, A, 256);

    // ---- classifier ----
    cls_k<<<(N_NODES + TPB - 1) / TPB, TPB, 0, stream>>>(A, clsW, clsb, out);
}

// Round 7
// 955.134 us; speedup vs baseline: 1.1960x; 1.1960x over previous
//
#include <hip/hip_runtime.h>
#include <math.h>

#define N_NODES 50000
#define N_EDGES 800000
#define TPB 256

// ---------------- register-blocked f32 GEMM ----------------
// out[M,NO] = act( [A1 | A2] @ [W1 ; W2] + bias ),  K = K1 + K2
// BM=128, BN_ in {128,64}, BK=16, 256 threads.
// Micro-tile: rows {tm*4..+3, 64+tm*4..+3}, cols {tn*4..+3 (,64+tn*4..+3)}.
// sA reads: 16 unique addrs spanning floats 0..63 -> 2-way bank alias (free).
// sB reads: 4 unique addrs/wave (broadcast) -> conflict-free.
template<int ACT, int BN_>
__global__ __launch_bounds__(256) void gemm_f32(
    const float* __restrict__ A1, int K1, const float* __restrict__ A2, int K2,
    const float* __restrict__ W1, const float* __restrict__ W2,
    const float* __restrict__ bias, float* __restrict__ out, int NO) {
    constexpr int BM = 128, BK = 16;
    constexpr int NJ = BN_ / 16;            // 8 or 4 cols per thread
    __shared__ float sA[BK][BM + 4];
    __shared__ float sB[BK][BN_ + 4];
    const int K = K1 + K2;
    const int tid = threadIdx.x;
    const int tm = tid & 15, tn = tid >> 4;      // 16x16 thread grid
    const int row0 = blockIdx.y * BM;
    const int col0 = blockIdx.x * BN_;
    float acc[8][NJ] = {};

    for (int k0 = 0; k0 < K; k0 += BK) {
        // stage A (BM x BK, transposed into sA[kk][m]); coalesced along k
#pragma unroll
        for (int j = 0; j < 8; ++j) {
            int e = tid + j * 256;
            int kk = e & 15, m = e >> 4;
            int kg = k0 + kk, mg = row0 + m;
            float v = 0.f;
            if (mg < N_NODES) {
                if (kg < K1) v = A1[(size_t)mg * K1 + kg];
                else if (kg < K) v = A2[(size_t)mg * K2 + (kg - K1)];
            }
            sA[kk][m] = v;
        }
        // stage B (BK x BN_); coalesced along n
#pragma unroll
        for (int j = 0; j < BK * BN_ / 256; ++j) {
            int e = tid + j * 256;
            int n = e & (BN_ - 1), kk = e / BN_;
            int kg = k0 + kk, ng = col0 + n;
            float v = 0.f;
            if (kg < K1) v = W1[(size_t)kg * NO + ng];
            else if (kg < K) v = W2[(size_t)(kg - K1) * NO + ng];
            sB[kk][n] = v;
        }
        __syncthreads();
#pragma unroll
        for (int kk = 0; kk < BK; ++kk) {
            float4 a0 = *(const float4*)&sA[kk][tm * 4];
            float4 a1 = *(const float4*)&sA[kk][64 + tm * 4];
            float a[8] = {a0.x, a0.y, a0.z, a0.w, a1.x, a1.y, a1.z, a1.w};
            float b[NJ];
            float4 b0 = *(const float4*)&sB[kk][tn * 4];
            b[0] = b0.x; b[1] = b0.y; b[2] = b0.z; b[3] = b0.w;
            if (BN_ == 128) {
                float4 b1 = *(const float4*)&sB[kk][64 + tn * 4];
                b[NJ - 4] = b1.x; b[NJ - 3] = b1.y; b[NJ - 2] = b1.z; b[NJ - 1] = b1.w;
            }
#pragma unroll
            for (int i = 0; i < 8; ++i)
#pragma unroll
                for (int j2 = 0; j2 < NJ; ++j2)
                    acc[i][j2] = fmaf(a[i], b[j2], acc[i][j2]);
        }
        __syncthreads();
    }
#pragma unroll
    for (int i = 0; i < 8; ++i) {
        int mg = row0 + ((i < 4) ? (tm * 4 + i) : (64 + tm * 4 + (i - 4)));
        if (mg >= N_NODES) continue;
#pragma unroll
        for (int jh = 0; jh < BN_ / 64; ++jh) {
            int ng = col0 + jh * 64 + tn * 4;
            float4 v;
            v.x = acc[i][jh * 4 + 0] + (bias ? bias[ng + 0] : 0.f);
            v.y = acc[i][jh * 4 + 1] + (bias ? bias[ng + 1] : 0.f);
            v.z = acc[i][jh * 4 + 2] + (bias ? bias[ng + 2] : 0.f);
            v.w = acc[i][jh * 4 + 3] + (bias ? bias[ng + 3] : 0.f);
            if (ACT) {
                v.x = fmaxf(v.x, 0.f); v.y = fmaxf(v.y, 0.f);
                v.z = fmaxf(v.z, 0.f); v.w = fmaxf(v.w, 0.f);
            }
            *(float4*)&out[(size_t)mg * NO + ng] = v;
        }
    }
}

// ---------------- CSR construction ----------------
__global__ void hist_k(const int* __restrict__ dst, int* __restrict__ deg) {
    int e = blockIdx.x * TPB + threadIdx.x;
    if (e < N_EDGES) atomicAdd(&deg[dst[e]], 1);
}

// single-block exclusive scan over deg -> rowptr (N_NODES+1 entries)
__global__ void scan_k(const int* __restrict__ deg, int* __restrict__ rowptr) {
    __shared__ int part[1024];
    const int tid = threadIdx.x;                     // 1024 threads
    const int CH = (N_NODES + 1023) / 1024;          // 49
    const int base = tid * CH;
    int s = 0;
    for (int i = 0; i < CH; ++i) {
        int idx = base + i;
        if (idx < N_NODES) s += deg[idx];
    }
    part[tid] = s;
    __syncthreads();
    for (int off = 1; off < 1024; off <<= 1) {
        int v = (tid >= off) ? part[tid - off] : 0;
        __syncthreads();
        part[tid] += v;
        __syncthreads();
    }
    int run = (tid == 0) ? 0 : part[tid - 1];
    for (int i = 0; i < CH; ++i) {
        int idx = base + i;
        if (idx < N_NODES) {
            rowptr[idx] = run;
            run += deg[idx];
        }
    }
    if (tid == 1023) rowptr[N_NODES] = run;
}

__global__ void fill_k(const int* __restrict__ src, const int* __restrict__ dst,
                       const int* __restrict__ rowptr, int* __restrict__ fill,
                       int* __restrict__ csr_src) {
    int e = blockIdx.x * TPB + threadIdx.x;
    if (e >= N_EDGES) return;
    int d = dst[e];
    int pos = rowptr[d] + atomicAdd(&fill[d], 1);
    csr_src[pos] = src[e];
}

// ---------------- gather aggregations (no scatter atomics) ----------------
// scalar version (small F, SAGE1's F=20)
template<int F, int BLK>
__global__ void gather_mean(const int* __restrict__ rowptr, const int* __restrict__ csr_src,
                            const float* __restrict__ feat, float* __restrict__ out) {
    int n = blockIdx.x;
    int c = threadIdx.x;
    if (c >= F) return;
    int e0 = rowptr[n], e1 = rowptr[n + 1];
    float acc = 0.f;
    for (int e = e0; e < e1; ++e)
        acc += feat[(size_t)csr_src[e] * F + c];
    out[(size_t)n * F + c] = acc / fmaxf((float)(e1 - e0), 1.0f);
}

// float4 version for F=128: 32 lanes/node, 8 nodes per 256-thread block
__global__ void gather_mean4(const int* __restrict__ rowptr, const int* __restrict__ csr_src,
                             const float4* __restrict__ feat4, float4* __restrict__ out4) {
    int tid = threadIdx.x;
    int n = blockIdx.x * 8 + (tid >> 5);
    int c = tid & 31;
    int e0 = rowptr[n], e1 = rowptr[n + 1];
    float4 acc = {0.f, 0.f, 0.f, 0.f};
    for (int e = e0; e < e1; ++e) {
        float4 v = feat4[(size_t)csr_src[e] * 32 + c];
        acc.x += v.x; acc.y += v.y; acc.z += v.z; acc.w += v.w;
    }
    float inv = 1.0f / fmaxf((float)(e1 - e0), 1.0f);
    acc.x *= inv; acc.y *= inv; acc.z *= inv; acc.w *= inv;
    out4[(size_t)n * 32 + c] = acc;
}

// per-(node,head) attention scores
__global__ void att_scores(const float* __restrict__ h, const float* __restrict__ att_src,
                           const float* __restrict__ att_dst, float* __restrict__ as_,
                           float* __restrict__ ad_) {
    int idx = blockIdx.x * TPB + threadIdx.x;
    if (idx >= N_NODES * 4) return;
    int n = idx >> 2, hd = idx & 3;
    const float* row = h + (size_t)n * 128 + hd * 32;
    float sa = 0.f, sd = 0.f;
    for (int c = 0; c < 32; ++c) {
        float v = row[c];
        sa = fmaf(v, att_src[hd * 32 + c], sa);
        sd = fmaf(v, att_dst[hd * 32 + c], sd);
    }
    as_[idx] = sa;
    ad_[idx] = sd;
}

// fused GAT aggregation, float4: online softmax + weighted gather + ELU
// 32 lanes/node (4 heads x 8 float4-lanes), 8 nodes per 256-thread block
__global__ void gat_gather4(const int* __restrict__ rowptr, const int* __restrict__ csr_src,
                            const float4* __restrict__ h4, const float* __restrict__ as_,
                            const float* __restrict__ ad_, const float* __restrict__ gb,
                            float4* __restrict__ out4) {
    int tid = threadIdx.x;
    int n = blockIdx.x * 8 + (tid >> 5);
    int c = tid & 31;              // float4 index within row; head = c>>3
    int hd = c >> 3;
    int e0 = rowptr[n], e1 = rowptr[n + 1];
    float ad = ad_[n * 4 + hd];
    float m = -INFINITY, s = 0.f;
    float4 acc = {0.f, 0.f, 0.f, 0.f};
    for (int e = e0; e < e1; ++e) {
        int sn = csr_src[e];
        float a = as_[sn * 4 + hd] + ad;
        a = a >= 0.f ? a : 0.2f * a;              // leaky_relu 0.2
        if (a > m) {                               // online softmax rescale
            float sc = __expf(m - a);
            s *= sc; acc.x *= sc; acc.y *= sc; acc.z *= sc; acc.w *= sc;
            m = a;
        }
        float ex = __expf(a - m);
        s += ex;
        float4 v = h4[(size_t)sn * 32 + c];
        acc.x = fmaf(v.x, ex, acc.x); acc.y = fmaf(v.y, ex, acc.y);
        acc.z = fmaf(v.z, ex, acc.z); acc.w = fmaf(v.w, ex, acc.w);
    }
    float inv = 1.0f / (s + 1e-16f);
    float4 r;
    r.x = acc.x * inv + gb[c * 4 + 0];
    r.y = acc.y * inv + gb[c * 4 + 1];
    r.z = acc.z * inv + gb[c * 4 + 2];
    r.w = acc.w * inv + gb[c * 4 + 3];
    r.x = r.x > 0.f ? r.x : expm1f(r.x);
    r.y = r.y > 0.f ? r.y : expm1f(r.y);
    r.z = r.z > 0.f ? r.z : expm1f(r.z);
    r.w = r.w > 0.f ? r.w : expm1f(r.w);
    out4[(size_t)n * 32 + c] = r;
}

// classifier: [N,256] @ [256,5] + b
__global__ void cls_k(const float* __restrict__ h, const float* __restrict__ W,
                      const float* __restrict__ b, float* __restrict__ out) {
    __shared__ float sW[256 * 5];
    for (int i = threadIdx.x; i < 1280; i += TPB) sW[i] = W[i];
    __syncthreads();
    int n = blockIdx.x * TPB + threadIdx.x;
    if (n >= N_NODES) return;
    const float4* row = (const float4*)(h + (size_t)n * 256);
    float acc[5] = {0.f, 0.f, 0.f, 0.f, 0.f};
    for (int k4 = 0; k4 < 64; ++k4) {
        float4 v = row[k4];
        const float* w = &sW[k4 * 4 * 5];
#pragma unroll
        for (int c = 0; c < 5; ++c) acc[c] = fmaf(v.x, w[c], acc[c]);
#pragma unroll
        for (int c = 0; c < 5; ++c) acc[c] = fmaf(v.y, w[5 + c], acc[c]);
#pragma unroll
        for (int c = 0; c < 5; ++c) acc[c] = fmaf(v.z, w[10 + c], acc[c]);
#pragma unroll
        for (int c = 0; c < 5; ++c) acc[c] = fmaf(v.w, w[15 + c], acc[c]);
    }
#pragma unroll
    for (int c = 0; c < 5; ++c) out[(size_t)n * 5 + c] = acc[c] + b[c];
}

extern "C" void kernel_launch(void* const* d_in, const int* in_sizes, int n_in,
                              void* d_out, int out_size, void* d_ws, size_t ws_size,
                              hipStream_t stream) {
    const float* x    = (const float*)d_in[0];
    const int*   ei   = (const int*)d_in[1];
    const float* s1Wl = (const float*)d_in[2];
    const float* s1Wr = (const float*)d_in[3];
    const float* s1b  = (const float*)d_in[4];
    const float* gW   = (const float*)d_in[5];
    const float* gas  = (const float*)d_in[6];
    const float* gad  = (const float*)d_in[7];
    const float* gb   = (const float*)d_in[8];
    const float* s2Wl = (const float*)d_in[9];
    const float* s2Wr = (const float*)d_in[10];
    const float* s2b  = (const float*)d_in[11];
    const float* clsW = (const float*)d_in[12];
    const float* clsb = (const float*)d_in[13];
    float* out = (float*)d_out;
    const int* src = ei;            // edge_index[0]
    const int* dst = ei + N_EDGES;  // edge_index[1]

    // ---- workspace layout (all fully rewritten each call; no stale reads) ----
    float* ws  = (float*)d_ws;
    float* A   = ws;                                  // N*256 (h1, then h3)
    float* C   = A + (size_t)N_NODES * 256;           // N*128 (gat h; later sage2 mean)
    float* D   = C + (size_t)N_NODES * 128;           // N*128 (sage1 mean(20); later gat out/h2)
    float* as_ = D + (size_t)N_NODES * 128;           // N*4
    float* ad_ = as_ + N_NODES * 4;                   // N*4
    int* deg     = (int*)(ad_ + N_NODES * 4);         // N
    int* fill    = deg + N_NODES;                     // N
    int* rowptr  = fill + N_NODES;                    // N+1
    int* csr_src = rowptr + N_NODES + 1;              // E

    const int MB = (N_NODES + 127) / 128;             // 391 row-blocks

    // ---- CSR build ----
    hipMemsetAsync(deg, 0, N_NODES * sizeof(int), stream);
    hipMemsetAsync(fill, 0, N_NODES * sizeof(int), stream);
    hist_k<<<(N_EDGES + TPB - 1) / TPB, TPB, 0, stream>>>(dst, deg);
    scan_k<<<1, 1024, 0, stream>>>(deg, rowptr);
    fill_k<<<(N_EDGES + TPB - 1) / TPB, TPB, 0, stream>>>(src, dst, rowptr, fill, csr_src);

    // ---- SAGE1:  A = relu([mean(x) | x] @ [Wl ; Wr] + b),  K = 20+20 ----
    gather_mean<20, 64><<<N_NODES, 64, 0, stream>>>(rowptr, csr_src, x, D);
    gemm_f32<1, 128><<<dim3(2, MB), 256, 0, stream>>>(D, 20, x, 20, s1Wl, s1Wr, s1b, A, 256);

    // ---- GAT:  C = A @ gW,  K = 256  (BN=64 -> 782 blocks) ----
    gemm_f32<0, 64><<<dim3(2, MB), 256, 0, stream>>>(A, 256, nullptr, 0, gW, nullptr,
                                                     nullptr, C, 128);
    att_scores<<<(N_NODES * 4 + TPB - 1) / TPB, TPB, 0, stream>>>(C, gas, gad, as_, ad_);
    gat_gather4<<<N_NODES / 8, 256, 0, stream>>>(rowptr, csr_src, (const float4*)C,
                                                 as_, ad_, gb, (float4*)D);

    // ---- SAGE2:  A = relu([mean(D) | D] @ [Wl ; Wr] + b),  K = 128+128 ----
    gather_mean4<<<N_NODES / 8, 256, 0, stream>>>(rowptr, csr_src, (const float4*)D,
                                                  (float4*)C);
    gemm_f32<1, 128><<<dim3(2, MB), 256, 0, stream>>>(C, 128, D, 128, s2Wl, s2Wr, s2b, A, 256);

    // ---- classifier ----
    cls_k<<<(N_NODES + TPB - 1) / TPB, TPB, 0, stream>>>(A, clsW, clsb, out);
}